// Round 25
// baseline (260.491 us; speedup 1.0000x reference)
//
#include <hip/hip_runtime.h>

#define N 8192
#define D 512
#define KNEI 10
#define NC 8
#define GSPLIT 16
#define TRS 20
#define NTOT (GSPLIT * 2 * NC)  // 256 candidates per row

typedef __attribute__((ext_vector_type(8))) short bfv8;
typedef __attribute__((ext_vector_type(8))) unsigned short usv8;
typedef __attribute__((ext_vector_type(4))) float fv4;
typedef unsigned int uint32;

#define GLOAD_LDS16(gp, lp)                                                  \
  __builtin_amdgcn_global_load_lds(                                          \
      (const __attribute__((address_space(1))) void*)(gp),                   \
      (__attribute__((address_space(3))) void*)(lp), 16, 0, 0)

__device__ inline unsigned short f2bf(float f) {
  unsigned int u = __float_as_uint(f);
  return (unsigned short)((u + 0x7fffu + ((u >> 16) & 1u)) >> 16);
}

// ---------------------------------------------------------------------------
// Kernel 0 (FUSED): per-row fp32 sq + fp32->bf16 cvt in one pass.
// sq: identical lane pattern / summation chain as validated row_sq kernel.
// cvt: identical f2bf on 8 contiguous elems/lane (row is L1/L2-hot from the
// sq phase). Both outputs bit-identical to the previous two kernels; saves
// one launch + a 16 MB HBM re-read.
// ---------------------------------------------------------------------------
__global__ __launch_bounds__(256) void sq_cvt_kernel(const float* __restrict__ x,
                                                     float* __restrict__ sq,
                                                     unsigned short* __restrict__ xb) {
  const int wave = threadIdx.x >> 6;
  const int lane = threadIdx.x & 63;
  const int row = blockIdx.x * 4 + wave;
  const float* xr = x + (size_t)row * D;

  float s = 0.f;
  if (lane < 32) {
    const int leaf = lane >> 3;
    const int j = lane & 7;
    const float* a = xr + leaf * 128;
    float v = a[j];
    s = __fmul_rn(v, v);
#pragma unroll
    for (int i = 8; i < 128; i += 8) {
      v = a[i + j];
      s = __fadd_rn(s, __fmul_rn(v, v));
    }
  }
  float t1 = __shfl_xor(s, 1);
  s = __fadd_rn(s, t1);
  float t2 = __shfl_xor(s, 2);
  s = __fadd_rn(s, t2);
  float t4 = __shfl_xor(s, 4);
  s = __fadd_rn(s, t4);
  const float L0 = __shfl(s, 0);
  const float L1 = __shfl(s, 8);
  const float L2 = __shfl(s, 16);
  const float L3 = __shfl(s, 24);
  const float total = __fadd_rn(__fadd_rn(L0, L1), __fadd_rn(L2, L3));
  if (lane == 0) sq[row] = total;

  // cvt: 8 contiguous per lane (row hot in cache).
  const float4 a4 = *(const float4*)(xr + lane * 8);
  const float4 b4 = *(const float4*)(xr + lane * 8 + 4);
  usv8 o;
  o[0] = f2bf(a4.x); o[1] = f2bf(a4.y); o[2] = f2bf(a4.z); o[3] = f2bf(a4.w);
  o[4] = f2bf(b4.x); o[5] = f2bf(b4.y); o[6] = f2bf(b4.z); o[7] = f2bf(b4.w);
  *(usv8*)(xb + (size_t)row * D + lane * 8) = o;
}

// ---------------------------------------------------------------------------
// Kernel 1: r22 half-height fat-tile (measured 132.5) + STAGING POINTER
// STRENGTH-REDUCTION (single delta): the 6 per-lane 64-bit global source
// addresses are computed once per jt and incremented +64 elems per kt
// (12 VALU/kt vs ~30-40 recomputed). VALUBusy 55% says we're VALU-issue
// bound; staged bytes/layout/MFMA order/selection unchanged -> ck
// bit-identical.
// ---------------------------------------------------------------------------
__global__ __launch_bounds__(256, 4) void knn_gemm_mfma(
    const unsigned short* __restrict__ xb, const float* __restrict__ sq,
    uint32* __restrict__ ck) {
  __shared__ __align__(16) unsigned short stage[64 * 64 + 128 * 64];  // 24576 B
  __shared__ float sqj_all[512];                                      //  2048 B
  unsigned short* As = stage;             // 64x64 bf16
  unsigned short* Bs = stage + 64 * 64;   // 128x64 bf16
  float* Ct = (float*)stage;              // 64x68 f32 (aliases)
  uint32* xch = (uint32*)stage;           // pair-merge exchange (aliases)

  const int tid = threadIdx.x;
  const int lane = tid & 63;
  const int wave = tid >> 6;
  const int wm = wave >> 1;
  const int wn = wave & 1;
  const int m = lane & 15;
  const int kg = lane >> 4;
  const int ibase = blockIdx.x * 64;
  const int jstart = blockIdx.y * (N / GSPLIT);

  const int srow = lane >> 3;
  const int schunk = lane & 7;
  const int sko = (schunk ^ srow) * 8;

  sqj_all[tid] = sq[jstart + tid];
  sqj_all[256 + tid] = sq[jstart + 256 + tid];

  uint32 bk[NC];
#pragma unroll
  for (int t = 0; t < NC; ++t) bk[t] = 0xffffffffu;

  const int selrow = tid & 63;
  const int selhalf = (tid >> 6) & 1;
  const int cchalf = tid >> 7;
  const float sqi_own = sq[ibase + selrow];

  // A source pointers: jt-invariant bases.
  const unsigned short* baseA0 =
      xb + (size_t)(ibase + wave * 8 + srow) * D + sko;
  const unsigned short* baseA1 = baseA0 + (size_t)32 * D;

#pragma unroll 1
  for (int jt = 0; jt < 4; ++jt) {
    const int jb128 = jstart + jt * 128;

    const unsigned short* qA0 = baseA0;
    const unsigned short* qA1 = baseA1;
    const unsigned short* qB0 =
        xb + (size_t)(jb128 + wave * 8 + srow) * D + sko;
    const unsigned short* qB1 = qB0 + (size_t)32 * D;
    const unsigned short* qB2 = qB0 + (size_t)64 * D;
    const unsigned short* qB3 = qB0 + (size_t)96 * D;

    fv4 acc[2][4];
#pragma unroll
    for (int fi = 0; fi < 2; ++fi)
#pragma unroll
      for (int fj = 0; fj < 4; ++fj) acc[fi][fj] = (fv4)(0.f);

#pragma unroll 1
    for (int kt = 0; kt < 8; ++kt) {
      __syncthreads();  // prior frag/Ct/xch reads done; staging reusable
      GLOAD_LDS16(qA0, As + (wave * 8) * 64);
      GLOAD_LDS16(qA1, As + (wave * 8 + 32) * 64);
      GLOAD_LDS16(qB0, Bs + (wave * 8) * 64);
      GLOAD_LDS16(qB1, Bs + (wave * 8 + 32) * 64);
      GLOAD_LDS16(qB2, Bs + (wave * 8 + 64) * 64);
      GLOAD_LDS16(qB3, Bs + (wave * 8 + 96) * 64);
      qA0 += 64; qA1 += 64;
      qB0 += 64; qB1 += 64; qB2 += 64; qB3 += 64;
      __syncthreads();  // staging visible

#pragma unroll
      for (int kh = 0; kh < 2; ++kh) {
        bfv8 af[2];
#pragma unroll
        for (int fi = 0; fi < 2; ++fi) {
          const int row = wm * 32 + fi * 16 + m;
          const int ch = (kh * 4 + kg) ^ (row & 7);
          af[fi] = *(const bfv8*)(As + row * 64 + ch * 8);
        }
#pragma unroll
        for (int fj = 0; fj < 4; ++fj) {
          const int row = wn * 64 + fj * 16 + m;
          const int ch = (kh * 4 + kg) ^ (row & 7);
          const bfv8 b = *(const bfv8*)(Bs + row * 64 + ch * 8);
#pragma unroll
          for (int fi = 0; fi < 2; ++fi) {
            acc[fi][fj] = __builtin_amdgcn_mfma_f32_16x16x32_bf16(
                af[fi], b, acc[fi][fj], 0, 0, 0);
          }
        }
      }
    }
    __syncthreads();  // frag reads done; Ct may overwrite staging

#pragma unroll 1
    for (int p = 0; p < 2; ++p) {
      if (wn == p) {
#pragma unroll
        for (int fi = 0; fi < 2; ++fi)
#pragma unroll
          for (int fj = 0; fj < 4; ++fj)
            *(fv4*)(&Ct[(fj * 16 + m) * 68 + wm * 32 + fi * 16 + kg * 4]) =
                acc[fi][fj];
      }
      __syncthreads();

      const int jbase = jb128 + p * 64;
      const int cbase = selhalf * 32 + cchalf * 16;
#pragma unroll 8
      for (int cc = 0; cc < 16; ++cc) {
        const int c = cbase + cc;
        const float d = fmaxf(
            sqi_own - 2.f * Ct[c * 68 + selrow] + sqj_all[jt * 128 + p * 64 + c],
            0.f);
        const uint32 key = ((uint32)f2bf(d) << 16) | (uint32)(jbase + c);
        if (key < bk[NC - 1]) {
          uint32 kv = key;
#pragma unroll
          for (int t = 0; t < NC; ++t) {
            if (kv < bk[t]) {
              const uint32 tmp = bk[t];
              bk[t] = kv;
              kv = tmp;
            }
          }
        }
      }
      __syncthreads();  // selection Ct reads done before next transpose/stage
    }
  }

  // Pair-merge: union of sub-range top-8s -> class top-8 (set-identical).
  if (cchalf == 1) {
#pragma unroll
    for (int t = 0; t < NC; ++t) xch[(tid - 128) * NC + t] = bk[t];
  }
  __syncthreads();
  if (cchalf == 0) {
#pragma unroll
    for (int t2 = 0; t2 < NC; ++t2) {
      uint32 kv = xch[tid * NC + t2];
      if (kv < bk[NC - 1]) {
#pragma unroll
        for (int t = 0; t < NC; ++t) {
          if (kv < bk[t]) {
            const uint32 tmp = bk[t];
            bk[t] = kv;
            kv = tmp;
          }
        }
      }
    }
    const size_t obase =
        ((size_t)(ibase + selrow) * (GSPLIT * 2) + blockIdx.y * 2 + selhalf) *
        NC;
#pragma unroll
    for (int t = 0; t < NC; ++t) ck[obase + t] = bk[t];
  }
}

// ---------------------------------------------------------------------------
// Kernel 2: merge — r21 measured form (group-of-4 rescore). UNCHANGED.
// ---------------------------------------------------------------------------
__global__ __launch_bounds__(256) void merge_kernel(const float* __restrict__ x,
                                                    const float* __restrict__ sq,
                                                    const uint32* __restrict__ ck,
                                                    float* __restrict__ out) {
  __shared__ double zsh[4][TRS];
  __shared__ int jsh[4][TRS];
  __shared__ int jout[4][KNEI];

  const int wave = threadIdx.x >> 6;
  const int lane = threadIdx.x & 63;
  const int i = blockIdx.x * 4 + wave;

  const float4 xiA = *(const float4*)(x + (size_t)i * D + lane * 8);
  const float4 xiB = *(const float4*)(x + (size_t)i * D + lane * 8 + 4);
  const float sqi = sq[i];

  const uint32* ckr = ck + (size_t)i * NTOT + lane * 4;
  uint32 l0 = ckr[0], l1 = ckr[1], l2 = ckr[2], l3 = ckr[3];

  // (1) top-20 by packed key (bf16 score, then lower index — keys unique).
  int myselj = 0;
#pragma unroll 1
  for (int slot = 0; slot < TRS; ++slot) {
    uint32 r = min(min(l0, l1), min(l2, l3));
#pragma unroll
    for (int off = 32; off; off >>= 1) r = min(r, __shfl_xor(r, off));
    if (lane == slot) myselj = (int)(r & 0xffffu);
    if (l0 == r) l0 = 0xffffffffu;
    if (l1 == r) l1 = 0xffffffffu;
    if (l2 == r) l2 = 0xffffffffu;
    if (l3 == r) l3 = 0xffffffffu;
  }

  // (2) fp64 rescore — groups of 4 for ILP; per-candidate numerics unchanged.
  double myz = 0.0;
#pragma unroll 1
  for (int g = 0; g < TRS; g += 4) {
    int jv[4];
#pragma unroll
    for (int u = 0; u < 4; ++u) jv[u] = __shfl(myselj, g + u);
    double part[4];
#pragma unroll
    for (int u = 0; u < 4; ++u) {
      const float4 a = *(const float4*)(x + (size_t)jv[u] * D + lane * 8);
      const float4 b = *(const float4*)(x + (size_t)jv[u] * D + lane * 8 + 4);
      part[u] = (double)xiA.x * a.x + (double)xiA.y * a.y +
                (double)xiA.z * a.z + (double)xiA.w * a.w +
                (double)xiB.x * b.x + (double)xiB.y * b.y +
                (double)xiB.z * b.z + (double)xiB.w * b.w;
    }
#pragma unroll
    for (int off = 32; off; off >>= 1) {
#pragma unroll
      for (int u = 0; u < 4; ++u) part[u] += __shfl_xor(part[u], off);
    }
#pragma unroll
    for (int u = 0; u < 4; ++u) {
      if (lane == g + u) {
        const float G = (float)part[u];
        const float y = __fsub_rn(sqi, __fmul_rn(2.0f, G));
        myz = (double)y + (double)sq[myselj];
      }
    }
  }
  if (lane < TRS) {
    zsh[wave][lane] = myz;
    jsh[wave][lane] = myselj;
  }
  __syncthreads();

  // (3) serial top-10, eps tie-break — comparator identical to rounds 3-7.
  if (lane == 0) {
    unsigned int used = 0u;
    for (int slot = 0; slot < KNEI; ++slot) {
      int b = -1;
      double zb = 0.0;
      for (int c = 0; c < TRS; ++c) {
        if ((used >> c) & 1u) continue;
        const double zc = zsh[wave][c];
        if (b < 0) {
          b = c;
          zb = zc;
          continue;
        }
        const double eps = 1.25e-7 * fabs(zb);
        bool better;
        if (zc < zb - eps) better = true;
        else if (zc > zb + eps) better = false;
        else better = (jsh[wave][c] < jsh[wave][b]);
        if (better) {
          b = c;
          zb = zc;
        }
      }
      used |= (1u << b);
      jout[wave][slot] = jsh[wave][b];
    }
  }
  __syncthreads();

  // (4) smoothed = 0.5*x + 0.05 * sum(neighbors); 8 dims per lane.
  float4 sA = {0.f, 0.f, 0.f, 0.f}, sB = {0.f, 0.f, 0.f, 0.f};
#pragma unroll
  for (int mth = 0; mth < KNEI; ++mth) {
    const int j = jout[wave][mth];
    const float4 a = *(const float4*)(x + (size_t)j * D + lane * 8);
    const float4 b = *(const float4*)(x + (size_t)j * D + lane * 8 + 4);
    sA.x += a.x; sA.y += a.y; sA.z += a.z; sA.w += a.w;
    sB.x += b.x; sB.y += b.y; sB.z += b.z; sB.w += b.w;
  }
  float4 oA, oB;
  oA.x = 0.5f * xiA.x + 0.05f * sA.x;
  oA.y = 0.5f * xiA.y + 0.05f * sA.y;
  oA.z = 0.5f * xiA.z + 0.05f * sA.z;
  oA.w = 0.5f * xiA.w + 0.05f * sA.w;
  oB.x = 0.5f * xiB.x + 0.05f * sB.x;
  oB.y = 0.5f * xiB.y + 0.05f * sB.y;
  oB.z = 0.5f * xiB.z + 0.05f * sB.z;
  oB.w = 0.5f * xiB.w + 0.05f * sB.w;
  *(float4*)(out + (size_t)i * D + lane * 8) = oA;
  *(float4*)(out + (size_t)i * D + lane * 8 + 4) = oB;
}

// ---------------------------------------------------------------------------
extern "C" void kernel_launch(void* const* d_in, const int* in_sizes, int n_in,
                              void* d_out, int out_size, void* d_ws, size_t ws_size,
                              hipStream_t stream) {
  const float* x = (const float*)d_in[0];
  float* out = (float*)d_out;

  char* ws = (char*)d_ws;
  float* sq = (float*)ws;                              // 32 KB
  unsigned short* xb = (unsigned short*)(ws + 32768);  // 8 MB
  uint32* ck = (uint32*)(ws + 32768 + 8388608);        // 8 MB

  sq_cvt_kernel<<<N / 4, 256, 0, stream>>>(x, sq, xb);
  knn_gemm_mfma<<<dim3(N / 64, GSPLIT), 256, 0, stream>>>(xb, sq, ck);
  merge_kernel<<<N / 4, 256, 0, stream>>>(x, sq, ck, out);
}

// Round 26
// 251.670 us; speedup vs baseline: 1.0351x; 1.0351x over previous
//
#include <hip/hip_runtime.h>

#define N 8192
#define D 512
#define KNEI 10
#define NC 8
#define GSPLIT 16
#define TRS 20
#define NTOT (GSPLIT * 2 * NC)  // 256 candidates per row

typedef __attribute__((ext_vector_type(8))) short bfv8;
typedef __attribute__((ext_vector_type(8))) unsigned short usv8;
typedef __attribute__((ext_vector_type(4))) float fv4;
typedef unsigned int uint32;

#define GLOAD_LDS16(gp, lp)                                                  \
  __builtin_amdgcn_global_load_lds(                                          \
      (const __attribute__((address_space(1))) void*)(gp),                   \
      (__attribute__((address_space(3))) void*)(lp), 16, 0, 0)

__device__ inline unsigned short f2bf(float f) {
  unsigned int u = __float_as_uint(f);
  return (unsigned short)((u + 0x7fffu + ((u >> 16) & 1u)) >> 16);
}

// ---------------------------------------------------------------------------
// Kernel 0: per-row fp32 sq (r22-validated separate form; fusion reverted to
// disambiguate r25's +10.6 us residual anomaly from machine noise).
// ---------------------------------------------------------------------------
__global__ __launch_bounds__(256) void row_sq_np_kernel(const float* __restrict__ x,
                                                        float* __restrict__ sq) {
  const int wave = threadIdx.x >> 6;
  const int lane = threadIdx.x & 63;
  const int row = blockIdx.x * 4 + wave;
  const float* xr = x + (size_t)row * D;

  float s = 0.f;
  if (lane < 32) {
    const int leaf = lane >> 3;
    const int j = lane & 7;
    const float* a = xr + leaf * 128;
    float v = a[j];
    s = __fmul_rn(v, v);
#pragma unroll
    for (int i = 8; i < 128; i += 8) {
      v = a[i + j];
      s = __fadd_rn(s, __fmul_rn(v, v));
    }
  }
  float t1 = __shfl_xor(s, 1);
  s = __fadd_rn(s, t1);
  float t2 = __shfl_xor(s, 2);
  s = __fadd_rn(s, t2);
  float t4 = __shfl_xor(s, 4);
  s = __fadd_rn(s, t4);
  const float L0 = __shfl(s, 0);
  const float L1 = __shfl(s, 8);
  const float L2 = __shfl(s, 16);
  const float L3 = __shfl(s, 24);
  const float total = __fadd_rn(__fadd_rn(L0, L1), __fadd_rn(L2, L3));
  if (lane == 0) sq[row] = total;
}

// ---------------------------------------------------------------------------
// Kernel 0b: fp32 -> bf16 (RTNE) — r22-validated separate form.
// ---------------------------------------------------------------------------
__global__ __launch_bounds__(256) void cvt_bf16_kernel(const float* __restrict__ x,
                                                       unsigned short* __restrict__ xb) {
  const int base = (blockIdx.x * 256 + threadIdx.x) * 8;
  const float4 a = *(const float4*)(x + base);
  const float4 b = *(const float4*)(x + base + 4);
  usv8 o;
  o[0] = f2bf(a.x); o[1] = f2bf(a.y); o[2] = f2bf(a.z); o[3] = f2bf(a.w);
  o[4] = f2bf(b.x); o[5] = f2bf(b.y); o[6] = f2bf(b.z); o[7] = f2bf(b.w);
  *(usv8*)(xb + base) = o;
}

// ---------------------------------------------------------------------------
// Kernel 1: r25 half-height fat-tile + pointer strength-reduction — measured
// 127.7 us (best knn; VGPR 48, VALUBusy 58). UNCHANGED from round 25.
// ---------------------------------------------------------------------------
__global__ __launch_bounds__(256, 4) void knn_gemm_mfma(
    const unsigned short* __restrict__ xb, const float* __restrict__ sq,
    uint32* __restrict__ ck) {
  __shared__ __align__(16) unsigned short stage[64 * 64 + 128 * 64];  // 24576 B
  __shared__ float sqj_all[512];                                      //  2048 B
  unsigned short* As = stage;             // 64x64 bf16
  unsigned short* Bs = stage + 64 * 64;   // 128x64 bf16
  float* Ct = (float*)stage;              // 64x68 f32 (aliases)
  uint32* xch = (uint32*)stage;           // pair-merge exchange (aliases)

  const int tid = threadIdx.x;
  const int lane = tid & 63;
  const int wave = tid >> 6;
  const int wm = wave >> 1;
  const int wn = wave & 1;
  const int m = lane & 15;
  const int kg = lane >> 4;
  const int ibase = blockIdx.x * 64;
  const int jstart = blockIdx.y * (N / GSPLIT);

  const int srow = lane >> 3;
  const int schunk = lane & 7;
  const int sko = (schunk ^ srow) * 8;

  sqj_all[tid] = sq[jstart + tid];
  sqj_all[256 + tid] = sq[jstart + 256 + tid];

  uint32 bk[NC];
#pragma unroll
  for (int t = 0; t < NC; ++t) bk[t] = 0xffffffffu;

  const int selrow = tid & 63;
  const int selhalf = (tid >> 6) & 1;
  const int cchalf = tid >> 7;
  const float sqi_own = sq[ibase + selrow];

  // A source pointers: jt-invariant bases.
  const unsigned short* baseA0 =
      xb + (size_t)(ibase + wave * 8 + srow) * D + sko;
  const unsigned short* baseA1 = baseA0 + (size_t)32 * D;

#pragma unroll 1
  for (int jt = 0; jt < 4; ++jt) {
    const int jb128 = jstart + jt * 128;

    const unsigned short* qA0 = baseA0;
    const unsigned short* qA1 = baseA1;
    const unsigned short* qB0 =
        xb + (size_t)(jb128 + wave * 8 + srow) * D + sko;
    const unsigned short* qB1 = qB0 + (size_t)32 * D;
    const unsigned short* qB2 = qB0 + (size_t)64 * D;
    const unsigned short* qB3 = qB0 + (size_t)96 * D;

    fv4 acc[2][4];
#pragma unroll
    for (int fi = 0; fi < 2; ++fi)
#pragma unroll
      for (int fj = 0; fj < 4; ++fj) acc[fi][fj] = (fv4)(0.f);

#pragma unroll 1
    for (int kt = 0; kt < 8; ++kt) {
      __syncthreads();  // prior frag/Ct/xch reads done; staging reusable
      GLOAD_LDS16(qA0, As + (wave * 8) * 64);
      GLOAD_LDS16(qA1, As + (wave * 8 + 32) * 64);
      GLOAD_LDS16(qB0, Bs + (wave * 8) * 64);
      GLOAD_LDS16(qB1, Bs + (wave * 8 + 32) * 64);
      GLOAD_LDS16(qB2, Bs + (wave * 8 + 64) * 64);
      GLOAD_LDS16(qB3, Bs + (wave * 8 + 96) * 64);
      qA0 += 64; qA1 += 64;
      qB0 += 64; qB1 += 64; qB2 += 64; qB3 += 64;
      __syncthreads();  // staging visible

#pragma unroll
      for (int kh = 0; kh < 2; ++kh) {
        bfv8 af[2];
#pragma unroll
        for (int fi = 0; fi < 2; ++fi) {
          const int row = wm * 32 + fi * 16 + m;
          const int ch = (kh * 4 + kg) ^ (row & 7);
          af[fi] = *(const bfv8*)(As + row * 64 + ch * 8);
        }
#pragma unroll
        for (int fj = 0; fj < 4; ++fj) {
          const int row = wn * 64 + fj * 16 + m;
          const int ch = (kh * 4 + kg) ^ (row & 7);
          const bfv8 b = *(const bfv8*)(Bs + row * 64 + ch * 8);
#pragma unroll
          for (int fi = 0; fi < 2; ++fi) {
            acc[fi][fj] = __builtin_amdgcn_mfma_f32_16x16x32_bf16(
                af[fi], b, acc[fi][fj], 0, 0, 0);
          }
        }
      }
    }
    __syncthreads();  // frag reads done; Ct may overwrite staging

#pragma unroll 1
    for (int p = 0; p < 2; ++p) {
      if (wn == p) {
#pragma unroll
        for (int fi = 0; fi < 2; ++fi)
#pragma unroll
          for (int fj = 0; fj < 4; ++fj)
            *(fv4*)(&Ct[(fj * 16 + m) * 68 + wm * 32 + fi * 16 + kg * 4]) =
                acc[fi][fj];
      }
      __syncthreads();

      const int jbase = jb128 + p * 64;
      const int cbase = selhalf * 32 + cchalf * 16;
#pragma unroll 8
      for (int cc = 0; cc < 16; ++cc) {
        const int c = cbase + cc;
        const float d = fmaxf(
            sqi_own - 2.f * Ct[c * 68 + selrow] + sqj_all[jt * 128 + p * 64 + c],
            0.f);
        const uint32 key = ((uint32)f2bf(d) << 16) | (uint32)(jbase + c);
        if (key < bk[NC - 1]) {
          uint32 kv = key;
#pragma unroll
          for (int t = 0; t < NC; ++t) {
            if (kv < bk[t]) {
              const uint32 tmp = bk[t];
              bk[t] = kv;
              kv = tmp;
            }
          }
        }
      }
      __syncthreads();  // selection Ct reads done before next transpose/stage
    }
  }

  // Pair-merge: union of sub-range top-8s -> class top-8 (set-identical).
  if (cchalf == 1) {
#pragma unroll
    for (int t = 0; t < NC; ++t) xch[(tid - 128) * NC + t] = bk[t];
  }
  __syncthreads();
  if (cchalf == 0) {
#pragma unroll
    for (int t2 = 0; t2 < NC; ++t2) {
      uint32 kv = xch[tid * NC + t2];
      if (kv < bk[NC - 1]) {
#pragma unroll
        for (int t = 0; t < NC; ++t) {
          if (kv < bk[t]) {
            const uint32 tmp = bk[t];
            bk[t] = kv;
            kv = tmp;
          }
        }
      }
    }
    const size_t obase =
        ((size_t)(ibase + selrow) * (GSPLIT * 2) + blockIdx.y * 2 + selhalf) *
        NC;
#pragma unroll
    for (int t = 0; t < NC; ++t) ck[obase + t] = bk[t];
  }
}

// ---------------------------------------------------------------------------
// Kernel 2: merge — r21 measured form (group-of-4 rescore). UNCHANGED.
// ---------------------------------------------------------------------------
__global__ __launch_bounds__(256) void merge_kernel(const float* __restrict__ x,
                                                    const float* __restrict__ sq,
                                                    const uint32* __restrict__ ck,
                                                    float* __restrict__ out) {
  __shared__ double zsh[4][TRS];
  __shared__ int jsh[4][TRS];
  __shared__ int jout[4][KNEI];

  const int wave = threadIdx.x >> 6;
  const int lane = threadIdx.x & 63;
  const int i = blockIdx.x * 4 + wave;

  const float4 xiA = *(const float4*)(x + (size_t)i * D + lane * 8);
  const float4 xiB = *(const float4*)(x + (size_t)i * D + lane * 8 + 4);
  const float sqi = sq[i];

  const uint32* ckr = ck + (size_t)i * NTOT + lane * 4;
  uint32 l0 = ckr[0], l1 = ckr[1], l2 = ckr[2], l3 = ckr[3];

  // (1) top-20 by packed key (bf16 score, then lower index — keys unique).
  int myselj = 0;
#pragma unroll 1
  for (int slot = 0; slot < TRS; ++slot) {
    uint32 r = min(min(l0, l1), min(l2, l3));
#pragma unroll
    for (int off = 32; off; off >>= 1) r = min(r, __shfl_xor(r, off));
    if (lane == slot) myselj = (int)(r & 0xffffu);
    if (l0 == r) l0 = 0xffffffffu;
    if (l1 == r) l1 = 0xffffffffu;
    if (l2 == r) l2 = 0xffffffffu;
    if (l3 == r) l3 = 0xffffffffu;
  }

  // (2) fp64 rescore — groups of 4 for ILP; per-candidate numerics unchanged.
  double myz = 0.0;
#pragma unroll 1
  for (int g = 0; g < TRS; g += 4) {
    int jv[4];
#pragma unroll
    for (int u = 0; u < 4; ++u) jv[u] = __shfl(myselj, g + u);
    double part[4];
#pragma unroll
    for (int u = 0; u < 4; ++u) {
      const float4 a = *(const float4*)(x + (size_t)jv[u] * D + lane * 8);
      const float4 b = *(const float4*)(x + (size_t)jv[u] * D + lane * 8 + 4);
      part[u] = (double)xiA.x * a.x + (double)xiA.y * a.y +
                (double)xiA.z * a.z + (double)xiA.w * a.w +
                (double)xiB.x * b.x + (double)xiB.y * b.y +
                (double)xiB.z * b.z + (double)xiB.w * b.w;
    }
#pragma unroll
    for (int off = 32; off; off >>= 1) {
#pragma unroll
      for (int u = 0; u < 4; ++u) part[u] += __shfl_xor(part[u], off);
    }
#pragma unroll
    for (int u = 0; u < 4; ++u) {
      if (lane == g + u) {
        const float G = (float)part[u];
        const float y = __fsub_rn(sqi, __fmul_rn(2.0f, G));
        myz = (double)y + (double)sq[myselj];
      }
    }
  }
  if (lane < TRS) {
    zsh[wave][lane] = myz;
    jsh[wave][lane] = myselj;
  }
  __syncthreads();

  // (3) serial top-10, eps tie-break — comparator identical to rounds 3-7.
  if (lane == 0) {
    unsigned int used = 0u;
    for (int slot = 0; slot < KNEI; ++slot) {
      int b = -1;
      double zb = 0.0;
      for (int c = 0; c < TRS; ++c) {
        if ((used >> c) & 1u) continue;
        const double zc = zsh[wave][c];
        if (b < 0) {
          b = c;
          zb = zc;
          continue;
        }
        const double eps = 1.25e-7 * fabs(zb);
        bool better;
        if (zc < zb - eps) better = true;
        else if (zc > zb + eps) better = false;
        else better = (jsh[wave][c] < jsh[wave][b]);
        if (better) {
          b = c;
          zb = zc;
        }
      }
      used |= (1u << b);
      jout[wave][slot] = jsh[wave][b];
    }
  }
  __syncthreads();

  // (4) smoothed = 0.5*x + 0.05 * sum(neighbors); 8 dims per lane.
  float4 sA = {0.f, 0.f, 0.f, 0.f}, sB = {0.f, 0.f, 0.f, 0.f};
#pragma unroll
  for (int mth = 0; mth < KNEI; ++mth) {
    const int j = jout[wave][mth];
    const float4 a = *(const float4*)(x + (size_t)j * D + lane * 8);
    const float4 b = *(const float4*)(x + (size_t)j * D + lane * 8 + 4);
    sA.x += a.x; sA.y += a.y; sA.z += a.z; sA.w += a.w;
    sB.x += b.x; sB.y += b.y; sB.z += b.z; sB.w += b.w;
  }
  float4 oA, oB;
  oA.x = 0.5f * xiA.x + 0.05f * sA.x;
  oA.y = 0.5f * xiA.y + 0.05f * sA.y;
  oA.z = 0.5f * xiA.z + 0.05f * sA.z;
  oA.w = 0.5f * xiA.w + 0.05f * sA.w;
  oB.x = 0.5f * xiB.x + 0.05f * sB.x;
  oB.y = 0.5f * xiB.y + 0.05f * sB.y;
  oB.z = 0.5f * xiB.z + 0.05f * sB.z;
  oB.w = 0.5f * xiB.w + 0.05f * sB.w;
  *(float4*)(out + (size_t)i * D + lane * 8) = oA;
  *(float4*)(out + (size_t)i * D + lane * 8 + 4) = oB;
}

// ---------------------------------------------------------------------------
extern "C" void kernel_launch(void* const* d_in, const int* in_sizes, int n_in,
                              void* d_out, int out_size, void* d_ws, size_t ws_size,
                              hipStream_t stream) {
  const float* x = (const float*)d_in[0];
  float* out = (float*)d_out;

  char* ws = (char*)d_ws;
  float* sq = (float*)ws;                              // 32 KB
  unsigned short* xb = (unsigned short*)(ws + 32768);  // 8 MB
  uint32* ck = (uint32*)(ws + 32768 + 8388608);        // 8 MB

  row_sq_np_kernel<<<N / 4, 256, 0, stream>>>(x, sq);
  cvt_bf16_kernel<<<(N * D) / (8 * 256), 256, 0, stream>>>(x, xb);
  knn_gemm_mfma<<<dim3(N / 64, GSPLIT), 256, 0, stream>>>(xb, sq, ck);
  merge_kernel<<<N / 4, 256, 0, stream>>>(x, sq, ck, out);
}